// Round 6
// baseline (409.881 us; speedup 1.0000x reference)
//
#include <hip/hip_runtime.h>
#include <hip/hip_bf16.h>
#include <math.h>

#define D 128
typedef unsigned int uint;
typedef unsigned short ushort;

using bf16x8 = __attribute__((ext_vector_type(8))) short;
using f32x4  = __attribute__((ext_vector_type(4))) float;

static __device__ __forceinline__ ushort f2b(float f) {
    __hip_bfloat16 h = __float2bfloat16(f);
    return __builtin_bit_cast(ushort, h);
}
static __device__ __forceinline__ float blo(uint u) {
    uint v = u << 16;
    return __builtin_bit_cast(float, v);
}
static __device__ __forceinline__ float bhi(uint u) {
    uint v = u & 0xFFFF0000u;
    return __builtin_bit_cast(float, v);
}

// ---------------------------------------------------------------- degree histogram, 8 edges/thread
// coverage: e = t + i*T for t in [0,T) only  (t>=T threads MUST exit: fixed R5 bug)
__global__ void k_deg(const int* __restrict__ dst, int* __restrict__ deg, int E, int T) {
    int t = blockIdx.x * 256 + threadIdx.x;
    if (t >= T) return;
    int d[8]; bool ok[8];
#pragma unroll
    for (int i = 0; i < 8; ++i) {
        int e = t + i * T;
        ok[i] = e < E;
        d[i] = ok[i] ? dst[e] : 0;
    }
#pragma unroll
    for (int i = 0; i < 8; ++i)
        if (ok[i]) atomicAdd(&deg[d[i]], 1);
}

// ---------------------------------------------------------------- scans
__global__ void k_scan1(const int* __restrict__ deg, int* __restrict__ rowptr,
                        int* __restrict__ bsum, int nN) {
    __shared__ int s[256];
    int tid = threadIdx.x;
    int i = blockIdx.x * 256 + tid;
    int v = (i < nN) ? deg[i] : 0;
    s[tid] = v;
    __syncthreads();
#pragma unroll
    for (int o = 1; o < 256; o <<= 1) {
        int t = (tid >= o) ? s[tid - o] : 0;
        __syncthreads();
        s[tid] += t;
        __syncthreads();
    }
    if (i < nN) rowptr[i] = s[tid] - v;
    if (tid == 255) bsum[blockIdx.x] = s[255];
}

__global__ void k_scan2(int* __restrict__ bsum, int nb) {
    __shared__ int s[512];
    __shared__ int carry_s;
    int tid = threadIdx.x;
    if (tid == 0) carry_s = 0;
    __syncthreads();
    for (int base = 0; base < nb; base += 512) {
        int i = base + tid;
        int v = (i < nb) ? bsum[i] : 0;
        s[tid] = v;
        __syncthreads();
#pragma unroll
        for (int o = 1; o < 512; o <<= 1) {
            int t = (tid >= o) ? s[tid - o] : 0;
            __syncthreads();
            s[tid] += t;
            __syncthreads();
        }
        int carry = carry_s;
        if (i < nb) bsum[i] = s[tid] - v + carry;
        int total = s[511];
        __syncthreads();
        if (tid == 0) carry_s = carry + total;
        __syncthreads();
    }
}

__global__ void k_scan3(int* __restrict__ rowptr, const int* __restrict__ bsum,
                        int* __restrict__ cursor, int nN, int E) {
    int i = blockIdx.x * 256 + threadIdx.x;
    if (i < nN) {
        int r = rowptr[i] + bsum[blockIdx.x];
        rowptr[i] = r;
        cursor[i] = r;
    }
    if (i == 0) rowptr[nN] = E;
}

// ---------------------------------------------------------------- place edges, 8 edges/thread (phased for ILP)
__global__ void k_place(const int* __restrict__ src, const int* __restrict__ dst,
                        int* __restrict__ cursor, int* __restrict__ col, int E, int T) {
    int t = blockIdx.x * 256 + threadIdx.x;
    if (t >= T) return;
    int d[8], s[8]; bool ok[8];
#pragma unroll
    for (int i = 0; i < 8; ++i) {
        int e = t + i * T;
        ok[i] = e < E;
        d[i] = ok[i] ? dst[e] : 0;
        s[i] = ok[i] ? src[e] : 0;
    }
    int p[8];
#pragma unroll
    for (int i = 0; i < 8; ++i)
        p[i] = ok[i] ? atomicAdd(&cursor[d[i]], 1) : 0;
#pragma unroll
    for (int i = 0; i < 8; ++i)
        if (ok[i]) col[p[i]] = s[i];
}

// ---------------------------------------------------------------- x fp32 -> bf16 into Abuf cols 128..255
__global__ void k_cast(const float* __restrict__ x, ushort* __restrict__ Abuf, int n4) {
    int i = blockIdx.x * 256 + threadIdx.x;
    if (i >= n4) return;
    float4 v = *(const float4*)(x + (size_t)i * 4);
    int node = i >> 5;
    int coff = (i & 31) * 4;
    ushort4 o;
    o.x = f2b(v.x); o.y = f2b(v.y); o.z = f2b(v.z); o.w = f2b(v.w);
    *(ushort4*)(Abuf + (size_t)node * 256 + 128 + coff) = o;
}

// ---------------------------------------------------------------- all weight prep in one launch
__global__ void k_prepw(const float* __restrict__ Wl0, const float* __restrict__ Wr0,
                        const float* __restrict__ Wl1, const float* __restrict__ Wr1,
                        const float* __restrict__ Wl2, const float* __restrict__ Wr2,
                        ushort* __restrict__ Wtg0, ushort* __restrict__ Wtg1,
                        ushort* __restrict__ W2tg) {
    int idx = blockIdx.x * 256 + threadIdx.x;
    if (idx < 2 * 128 * 256) {
        int which = idx >> 15;
        int o = idx & 32767;
        int j = o >> 8, k = o & 255;
        const float* Wl = which ? Wl1 : Wl0;
        const float* Wr = which ? Wr1 : Wr0;
        float v = (k < 128) ? Wl[j * 128 + k] : Wr[j * 128 + (k - 128)];
        (which ? Wtg1 : Wtg0)[o] = f2b(v);
    } else {
        int o = idx - 2 * 128 * 256;
        if (o >= 80 * 128) return;
        int j = o >> 7, k = o & 127;
        float v = (j < 40) ? Wl2[j * 128 + k] : Wr2[(j - 40) * 128 + k];
        W2tg[o] = f2b(v);
    }
}

// ---------------------------------------------------------------- 128-dim mean-gather: 8 edge slots x 8 lanes x 32B
__global__ __launch_bounds__(256) void k_gather128(
    const ushort* __restrict__ feat, ushort* __restrict__ agg,
    const int* __restrict__ rowptr, const int* __restrict__ col, int nN)
{
    int node = blockIdx.x * 4 + (threadIdx.x >> 6);
    if (node >= nN) return;
    int lane = threadIdx.x & 63;
    int g = lane >> 3;          // edge slot 0..7
    int r = lane & 7;           // 32B chunk -> dims 16r..16r+15
    int beg = rowptr[node], end = rowptr[node + 1];
    float a[16];
#pragma unroll
    for (int i = 0; i < 16; ++i) a[i] = 0.f;

    for (int j = beg + g; j < end; j += 8) {
        int s = col[j];
        const ushort* p = feat + (size_t)s * 256 + r * 16;
        uint4 v0 = *(const uint4*)p;          // dims 16r..16r+7
        uint4 v1 = *(const uint4*)(p + 8);    // dims 16r+8..16r+15
        const uint* p0 = (const uint*)&v0;
        const uint* p1 = (const uint*)&v1;
#pragma unroll
        for (int i = 0; i < 4; ++i) {
            a[2 * i]     += blo(p0[i]);
            a[2 * i + 1] += bhi(p0[i]);
            a[8 + 2 * i]     += blo(p1[i]);
            a[8 + 2 * i + 1] += bhi(p1[i]);
        }
    }
#pragma unroll
    for (int i = 0; i < 16; ++i) {
        a[i] += __shfl_xor(a[i], 8);
        a[i] += __shfl_xor(a[i], 16);
        a[i] += __shfl_xor(a[i], 32);
    }
    if (g == 0) {
        float inv = 1.0f / (float)max(end - beg, 1);
        uint4 o0, o1;
        uint* q0 = (uint*)&o0;
        uint* q1 = (uint*)&o1;
#pragma unroll
        for (int i = 0; i < 4; ++i) {
            q0[i] = (uint)f2b(a[2 * i] * inv)     | ((uint)f2b(a[2 * i + 1] * inv) << 16);
            q1[i] = (uint)f2b(a[8 + 2 * i] * inv) | ((uint)f2b(a[8 + 2 * i + 1] * inv) << 16);
        }
        ushort* dsto = agg + (size_t)node * 256 + r * 16;
        *(uint4*)dsto = o0;
        *(uint4*)(dsto + 8) = o1;
    }
}

// ---------------------------------------------------------------- MFMA GEMM
// MODE 0: v += bias[j]; relu; out[m*ostride+j].
// MODE 1: j<40 -> P=out[m*40+j]; j>=40 -> R=out2[m*40+j-40] + bias[j-40].
template<int OUTJ, int KDIM, int SW, int MODE>
__global__ __launch_bounds__(256) void k_gemm_mfma(
    const ushort* __restrict__ A, int astride,
    const ushort* __restrict__ Wt, const float* __restrict__ bias,
    ushort* __restrict__ out, int ostride, ushort* __restrict__ out2, int nN)
{
    constexpr int NT = OUTJ / 16;
    constexpr int KSTEPS = KDIM / 32;
    __shared__ __align__(16) ushort Ws[OUTJ * SW];

    const int tid = threadIdx.x;
    constexpr int CHUNKS = OUTJ * KDIM / 8;
#pragma unroll
    for (int c = tid; c < CHUNKS; c += 256) {
        int row = c / (KDIM / 8);
        int ko  = (c % (KDIM / 8)) * 8;
        *(uint4*)(Ws + row * SW + ko) = *(const uint4*)(Wt + row * KDIM + ko);
    }
    __syncthreads();

    const int l = tid & 63, wv = tid >> 6;
    const int q = l >> 4, r = l & 15;
    const long long m0 = (long long)blockIdx.x * 128 + wv * 32;
    const int mA = (int)min(m0 + r, (long long)(nN - 1));
    const int mB = (int)min(m0 + 16 + r, (long long)(nN - 1));
    const ushort* pa = A + (size_t)mA * astride + q * 8;
    const ushort* pb = A + (size_t)mB * astride + q * 8;

    f32x4 acc[2][NT];
#pragma unroll
    for (int mt = 0; mt < 2; ++mt)
#pragma unroll
        for (int nt = 0; nt < NT; ++nt)
            acc[mt][nt] = (f32x4){0.f, 0.f, 0.f, 0.f};

    bf16x8 a0 = *(const bf16x8*)pa;
    bf16x8 a1 = *(const bf16x8*)pb;
#pragma unroll
    for (int ks = 0; ks < KSTEPS; ++ks) {
        bf16x8 a0n = a0, a1n = a1;
        if (ks + 1 < KSTEPS) {
            a0n = *(const bf16x8*)(pa + (ks + 1) * 32);
            a1n = *(const bf16x8*)(pb + (ks + 1) * 32);
        }
#pragma unroll
        for (int nt = 0; nt < NT; ++nt) {
            bf16x8 b = *(const bf16x8*)(Ws + (nt * 16 + r) * SW + ks * 32 + q * 8);
            acc[0][nt] = __builtin_amdgcn_mfma_f32_16x16x32_bf16(a0, b, acc[0][nt], 0, 0, 0);
            acc[1][nt] = __builtin_amdgcn_mfma_f32_16x16x32_bf16(a1, b, acc[1][nt], 0, 0, 0);
        }
        a0 = a0n; a1 = a1n;
    }

#pragma unroll
    for (int mt = 0; mt < 2; ++mt) {
#pragma unroll
        for (int i = 0; i < 4; ++i) {
            long long m = m0 + mt * 16 + q * 4 + i;
            if (m >= nN) continue;
#pragma unroll
            for (int nt = 0; nt < NT; ++nt) {
                int cc = nt * 16 + r;
                float v = acc[mt][nt][i];
                if (MODE == 0) {
                    v += bias[cc];
                    v = fmaxf(v, 0.f);
                    out[(size_t)m * ostride + cc] = f2b(v);
                } else {
                    if (cc < 40) out[(size_t)m * 40 + cc] = f2b(v);
                    else { v += bias[cc - 40]; out2[(size_t)m * 40 + (cc - 40)] = f2b(v); }
                }
            }
        }
    }
}

// ---------------------------------------------------------------- 40-dim mean-gather + self + log_softmax
__global__ __launch_bounds__(256) void k_gather40_lsm(
    const ushort* __restrict__ P, const ushort* __restrict__ R,
    const int* __restrict__ rowptr, const int* __restrict__ col,
    float* __restrict__ out, int nN)
{
    int node = blockIdx.x * 4 + (threadIdx.x >> 6);
    if (node >= nN) return;
    int lane = threadIdx.x & 63;
    int g = lane >> 3;          // edge slot 0..7
    int r = lane & 7;           // 16B chunk -> cols 8r..8r+7 (valid r<5)
    int beg = rowptr[node], end = rowptr[node + 1];
    float a[8];
#pragma unroll
    for (int i = 0; i < 8; ++i) a[i] = 0.f;

    for (int j = beg + g; j < end; j += 8) {
        int s = col[j];
        uint4 v = *(const uint4*)(P + (size_t)s * 40 + r * 8);
        const uint* p = (const uint*)&v;
#pragma unroll
        for (int i = 0; i < 4; ++i) {
            a[2 * i]     += blo(p[i]);
            a[2 * i + 1] += bhi(p[i]);
        }
    }
#pragma unroll
    for (int i = 0; i < 8; ++i) {
        a[i] += __shfl_xor(a[i], 8);
        a[i] += __shfl_xor(a[i], 16);
        a[i] += __shfl_xor(a[i], 32);
    }
    float inv = 1.0f / (float)max(end - beg, 1);
    uint4 rv = *(const uint4*)(R + (size_t)node * 40 + r * 8);
    const uint* pr = (const uint*)&rv;
    float vv[8];
    float mx = -INFINITY;
#pragma unroll
    for (int i = 0; i < 8; ++i) {
        float rc = (i & 1) ? bhi(pr[i >> 1]) : blo(pr[i >> 1]);
        int c = r * 8 + i;
        vv[i] = (c < 40) ? (a[i] * inv + rc) : -INFINITY;
        mx = fmaxf(mx, vv[i]);
    }
    mx = fmaxf(mx, __shfl_xor(mx, 1));
    mx = fmaxf(mx, __shfl_xor(mx, 2));
    mx = fmaxf(mx, __shfl_xor(mx, 4));
    float s = 0.f;
#pragma unroll
    for (int i = 0; i < 8; ++i) {
        int c = r * 8 + i;
        if (c < 40) s += __expf(vv[i] - mx);
    }
    s += __shfl_xor(s, 1);
    s += __shfl_xor(s, 2);
    s += __shfl_xor(s, 4);
    float lse = mx + __logf(s);
    if (g == 0 && r < 5) {
        float4 o0 = make_float4(vv[0] - lse, vv[1] - lse, vv[2] - lse, vv[3] - lse);
        float4 o1 = make_float4(vv[4] - lse, vv[5] - lse, vv[6] - lse, vv[7] - lse);
        *(float4*)(out + (size_t)node * 40 + r * 8)     = o0;
        *(float4*)(out + (size_t)node * 40 + r * 8 + 4) = o1;
    }
}

// ---------------------------------------------------------------- launch
extern "C" void kernel_launch(void* const* d_in, const int* in_sizes, int n_in,
                              void* d_out, int out_size, void* d_ws, size_t ws_size,
                              hipStream_t stream) {
    const float* x   = (const float*)d_in[0];
    const int*   ei  = (const int*)d_in[1];
    const float* Wl0 = (const float*)d_in[2];
    const float* Wr0 = (const float*)d_in[3];
    const float* b0  = (const float*)d_in[4];
    const float* Wl1 = (const float*)d_in[5];
    const float* Wr1 = (const float*)d_in[6];
    const float* b1  = (const float*)d_in[7];
    const float* Wl2 = (const float*)d_in[8];
    const float* Wr2 = (const float*)d_in[9];
    const float* b2  = (const float*)d_in[10];
    const int nN = in_sizes[0] / D;
    const int E  = in_sizes[1] / 2;
    const int* src = ei;
    const int* dst = ei + E;

    char* w = (char*)d_ws;
    auto alloc = [&](size_t bytes) { char* p = w; w += (bytes + 255) & ~(size_t)255; return p; };
    int*    deg    = (int*)   alloc((size_t)nN * 4);          // reused as cursor
    int*    rowptr = (int*)   alloc((size_t)(nN + 1) * 4);
    int*    bsum   = (int*)   alloc((size_t)((nN + 255) / 256) * 4);
    int*    col    = (int*)   alloc((size_t)E * 4);
    ushort* AbufA  = (ushort*)alloc((size_t)nN * 256 * 2);    // [agg | feat] bf16
    ushort* AbufB  = (ushort*)alloc((size_t)nN * 256 * 2);
    ushort* Wtg0   = (ushort*)alloc((size_t)128 * 256 * 2);
    ushort* Wtg1   = (ushort*)alloc((size_t)128 * 256 * 2);
    ushort* W2tg   = (ushort*)alloc((size_t)80 * 128 * 2);
    ushort* Pbuf   = AbufB;                    // [N,40] bf16 packed (AbufB dead by then)
    ushort* Rbuf   = AbufB + (size_t)nN * 40;  // [N,40] bf16
    float*  logits = (float*)d_out;
    int*    cursor = deg;

    const int NB        = (nN + 255) / 256;
    const int GATH_BLKS = (nN + 3) / 4;
    const int GEMM_BLKS = (nN + 127) / 128;
    const int PREPW_TOT = 2 * 128 * 256 + 80 * 128;
    const int T8        = (E + 7) / 8;                 // threads for 8-edge/thread kernels
    const int EDGE8_BLK = (T8 + 255) / 256;

    // ---- CSR build + casts + weight prep
    hipMemsetAsync(deg, 0, (size_t)nN * 4, stream);
    k_deg  <<<EDGE8_BLK, 256, 0, stream>>>(dst, deg, E, T8);
    k_scan1<<<NB, 256, 0, stream>>>(deg, rowptr, bsum, nN);
    k_scan2<<<1, 512, 0, stream>>>(bsum, NB);
    k_scan3<<<NB, 256, 0, stream>>>(rowptr, bsum, cursor, nN, E);
    k_place<<<EDGE8_BLK, 256, 0, stream>>>(src, dst, cursor, col, E, T8);
    k_cast <<<(nN * 32 + 255) / 256, 256, 0, stream>>>(x, AbufA, nN * 32);
    k_prepw<<<(PREPW_TOT + 255) / 256, 256, 0, stream>>>(
        Wl0, Wr0, Wl1, Wr1, Wl2, Wr2, Wtg0, Wtg1, W2tg);

    // ---- layer 0
    k_gather128<<<GATH_BLKS, 256, 0, stream>>>(AbufA + 128, AbufA, rowptr, col, nN);
    k_gemm_mfma<128, 256, 264, 0><<<GEMM_BLKS, 256, 0, stream>>>(
        AbufA, 256, Wtg0, b0, AbufB + 128, 256, nullptr, nN);

    // ---- layer 1
    k_gather128<<<GATH_BLKS, 256, 0, stream>>>(AbufB + 128, AbufB, rowptr, col, nN);
    k_gemm_mfma<128, 256, 264, 0><<<GEMM_BLKS, 256, 0, stream>>>(
        AbufB, 256, Wtg1, b1, AbufA + 128, 256, nullptr, nN);   // h1 -> AbufA cols 128+

    // ---- layer 2: project first, then 40-dim gather + log_softmax
    k_gemm_mfma<80, 128, 136, 1><<<GEMM_BLKS, 256, 0, stream>>>(
        AbufA + 128, 256, W2tg, b2, Pbuf, 40, Rbuf, nN);
    k_gather40_lsm<<<GATH_BLKS, 256, 0, stream>>>(Pbuf, Rbuf, rowptr, col, logits, nN);
}

// Round 8
// 385.581 us; speedup vs baseline: 1.0630x; 1.0630x over previous
//
#include <hip/hip_runtime.h>
#include <hip/hip_bf16.h>
#include <math.h>

#define D 128
typedef unsigned int uint;
typedef unsigned short ushort;

using bf16x8 = __attribute__((ext_vector_type(8))) short;
using f32x4  = __attribute__((ext_vector_type(4))) float;

static __device__ __forceinline__ ushort f2b(float f) {
    __hip_bfloat16 h = __float2bfloat16(f);
    return __builtin_bit_cast(ushort, h);
}
static __device__ __forceinline__ float blo(uint u) {
    uint v = u << 16;
    return __builtin_bit_cast(float, v);
}
static __device__ __forceinline__ float bhi(uint u) {
    uint v = u & 0xFFFF0000u;
    return __builtin_bit_cast(float, v);
}

// ---------------------------------------------------------------- degree histogram (simple, R4-proven)
__global__ void k_deg(const int* __restrict__ dst, int* __restrict__ deg, int E) {
    int e = blockIdx.x * 256 + threadIdx.x;
    if (e < E) atomicAdd(&deg[dst[e]], 1);
}

// ---------------------------------------------------------------- scans
__global__ void k_scan1(const int* __restrict__ deg, int* __restrict__ rowptr,
                        int* __restrict__ bsum, int nN) {
    __shared__ int s[256];
    int tid = threadIdx.x;
    int i = blockIdx.x * 256 + tid;
    int v = (i < nN) ? deg[i] : 0;
    s[tid] = v;
    __syncthreads();
#pragma unroll
    for (int o = 1; o < 256; o <<= 1) {
        int t = (tid >= o) ? s[tid - o] : 0;
        __syncthreads();
        s[tid] += t;
        __syncthreads();
    }
    if (i < nN) rowptr[i] = s[tid] - v;
    if (tid == 255) bsum[blockIdx.x] = s[255];
}

__global__ void k_scan2(int* __restrict__ bsum, int nb) {
    __shared__ int s[512];
    __shared__ int carry_s;
    int tid = threadIdx.x;
    if (tid == 0) carry_s = 0;
    __syncthreads();
    for (int base = 0; base < nb; base += 512) {
        int i = base + tid;
        int v = (i < nb) ? bsum[i] : 0;
        s[tid] = v;
        __syncthreads();
#pragma unroll
        for (int o = 1; o < 512; o <<= 1) {
            int t = (tid >= o) ? s[tid - o] : 0;
            __syncthreads();
            s[tid] += t;
            __syncthreads();
        }
        int carry = carry_s;
        if (i < nb) bsum[i] = s[tid] - v + carry;
        int total = s[511];
        __syncthreads();
        if (tid == 0) carry_s = carry + total;
        __syncthreads();
    }
}

__global__ void k_scan3(int* __restrict__ rowptr, const int* __restrict__ bsum,
                        int* __restrict__ cursor, int nN, int E) {
    int i = blockIdx.x * 256 + threadIdx.x;
    if (i < nN) {
        int r = rowptr[i] + bsum[blockIdx.x];
        rowptr[i] = r;
        cursor[i] = r;
    }
    if (i == 0) rowptr[nN] = E;
}

// ---------------------------------------------------------------- place edges (simple, R4-proven)
__global__ void k_place(const int* __restrict__ src, const int* __restrict__ dst,
                        int* __restrict__ cursor, int* __restrict__ col, int E) {
    int e = blockIdx.x * 256 + threadIdx.x;
    if (e < E) {
        int pos = atomicAdd(&cursor[dst[e]], 1);
        col[pos] = src[e];
    }
}

// ---------------------------------------------------------------- merged prep: x cast (idx < n4) + weight prep
__global__ void k_prep(const float* __restrict__ x, ushort* __restrict__ Abuf, int n4,
                       const float* __restrict__ Wl0, const float* __restrict__ Wr0,
                       const float* __restrict__ Wl1, const float* __restrict__ Wr1,
                       const float* __restrict__ Wl2, const float* __restrict__ Wr2,
                       ushort* __restrict__ Wtg0, ushort* __restrict__ Wtg1,
                       ushort* __restrict__ W2tg) {
    int idx = blockIdx.x * 256 + threadIdx.x;
    if (idx < n4) {
        float4 v = *(const float4*)(x + (size_t)idx * 4);
        int node = idx >> 5;
        int coff = (idx & 31) * 4;
        ushort4 o;
        o.x = f2b(v.x); o.y = f2b(v.y); o.z = f2b(v.z); o.w = f2b(v.w);
        *(ushort4*)(Abuf + (size_t)node * 256 + 128 + coff) = o;
        return;
    }
    int w = idx - n4;
    if (w < 2 * 128 * 256) {
        int which = w >> 15;
        int o = w & 32767;
        int j = o >> 8, k = o & 255;
        const float* Wl = which ? Wl1 : Wl0;
        const float* Wr = which ? Wr1 : Wr0;
        float v = (k < 128) ? Wl[j * 128 + k] : Wr[j * 128 + (k - 128)];
        (which ? Wtg1 : Wtg0)[o] = f2b(v);
    } else {
        int o = w - 2 * 128 * 256;
        if (o >= 80 * 128) return;
        int j = o >> 7, k = o & 127;
        float v = (j < 40) ? Wl2[j * 128 + k] : Wr2[(j - 40) * 128 + k];
        W2tg[o] = f2b(v);
    }
}

// ---------------------------------------------------------------- 128-dim mean-gather, 4 edge slots x 16 lanes x 16B (R4-proven)
__global__ __launch_bounds__(256) void k_gather128(
    const ushort* __restrict__ feat, ushort* __restrict__ agg,
    const int* __restrict__ rowptr, const int* __restrict__ col, int nN)
{
    int node = blockIdx.x * 4 + (threadIdx.x >> 6);
    if (node >= nN) return;
    int lane = threadIdx.x & 63;
    int g = lane >> 4;          // edge slot 0..3
    int r = lane & 15;          // 16B chunk -> dims 8r..8r+7
    int beg = rowptr[node], end = rowptr[node + 1];
    float a[8];
#pragma unroll
    for (int i = 0; i < 8; ++i) a[i] = 0.f;

    int j = beg + g;
    for (; j + 4 < end; j += 8) {          // 8 edges per unrolled iter (2 per slot)
        int s0 = col[j], s1 = col[j + 4];
        uint4 v0 = *(const uint4*)(feat + (size_t)s0 * 256 + r * 8);
        uint4 v1 = *(const uint4*)(feat + (size_t)s1 * 256 + r * 8);
        const uint* p0 = (const uint*)&v0;
        const uint* p1 = (const uint*)&v1;
#pragma unroll
        for (int i = 0; i < 4; ++i) {
            a[2 * i]     += blo(p0[i]) + blo(p1[i]);
            a[2 * i + 1] += bhi(p0[i]) + bhi(p1[i]);
        }
    }
    if (j < end) {
        int s0 = col[j];
        uint4 v0 = *(const uint4*)(feat + (size_t)s0 * 256 + r * 8);
        const uint* p0 = (const uint*)&v0;
#pragma unroll
        for (int i = 0; i < 4; ++i) {
            a[2 * i]     += blo(p0[i]);
            a[2 * i + 1] += bhi(p0[i]);
        }
    }
#pragma unroll
    for (int i = 0; i < 8; ++i) {
        a[i] += __shfl_xor(a[i], 16);
        a[i] += __shfl_xor(a[i], 32);
    }
    if (g == 0) {
        float inv = 1.0f / (float)max(end - beg, 1);
        uint4 o;
        uint* po = (uint*)&o;
#pragma unroll
        for (int i = 0; i < 4; ++i)
            po[i] = (uint)f2b(a[2 * i] * inv) | ((uint)f2b(a[2 * i + 1] * inv) << 16);
        *(uint4*)(agg + (size_t)node * 256 + r * 8) = o;
    }
}

// ---------------------------------------------------------------- MFMA GEMM
// MODE 0: v += bias[j]; relu; out[m*ostride+j].
// MODE 1: j<40 -> P=out[m*40+j]; j>=40 -> R=out2[m*40+j-40] + bias[j-40].
template<int OUTJ, int KDIM, int SW, int MODE>
__global__ __launch_bounds__(256) void k_gemm_mfma(
    const ushort* __restrict__ A, int astride,
    const ushort* __restrict__ Wt, const float* __restrict__ bias,
    ushort* __restrict__ out, int ostride, ushort* __restrict__ out2, int nN)
{
    constexpr int NT = OUTJ / 16;
    constexpr int KSTEPS = KDIM / 32;
    __shared__ __align__(16) ushort Ws[OUTJ * SW];

    const int tid = threadIdx.x;
    constexpr int CHUNKS = OUTJ * KDIM / 8;
#pragma unroll
    for (int c = tid; c < CHUNKS; c += 256) {
        int row = c / (KDIM / 8);
        int ko  = (c % (KDIM / 8)) * 8;
        *(uint4*)(Ws + row * SW + ko) = *(const uint4*)(Wt + row * KDIM + ko);
    }
    __syncthreads();

    const int l = tid & 63, wv = tid >> 6;
    const int q = l >> 4, r = l & 15;
    const long long m0 = (long long)blockIdx.x * 128 + wv * 32;
    const int mA = (int)min(m0 + r, (long long)(nN - 1));
    const int mB = (int)min(m0 + 16 + r, (long long)(nN - 1));
    const ushort* pa = A + (size_t)mA * astride + q * 8;
    const ushort* pb = A + (size_t)mB * astride + q * 8;

    f32x4 acc[2][NT];
#pragma unroll
    for (int mt = 0; mt < 2; ++mt)
#pragma unroll
        for (int nt = 0; nt < NT; ++nt)
            acc[mt][nt] = (f32x4){0.f, 0.f, 0.f, 0.f};

    bf16x8 a0 = *(const bf16x8*)pa;
    bf16x8 a1 = *(const bf16x8*)pb;
#pragma unroll
    for (int ks = 0; ks < KSTEPS; ++ks) {
        bf16x8 a0n = a0, a1n = a1;
        if (ks + 1 < KSTEPS) {
            a0n = *(const bf16x8*)(pa + (ks + 1) * 32);
            a1n = *(const bf16x8*)(pb + (ks + 1) * 32);
        }
#pragma unroll
        for (int nt = 0; nt < NT; ++nt) {
            bf16x8 b = *(const bf16x8*)(Ws + (nt * 16 + r) * SW + ks * 32 + q * 8);
            acc[0][nt] = __builtin_amdgcn_mfma_f32_16x16x32_bf16(a0, b, acc[0][nt], 0, 0, 0);
            acc[1][nt] = __builtin_amdgcn_mfma_f32_16x16x32_bf16(a1, b, acc[1][nt], 0, 0, 0);
        }
        a0 = a0n; a1 = a1n;
    }

#pragma unroll
    for (int mt = 0; mt < 2; ++mt) {
#pragma unroll
        for (int i = 0; i < 4; ++i) {
            long long m = m0 + mt * 16 + q * 4 + i;
            if (m >= nN) continue;
#pragma unroll
            for (int nt = 0; nt < NT; ++nt) {
                int cc = nt * 16 + r;
                float v = acc[mt][nt][i];
                if (MODE == 0) {
                    v += bias[cc];
                    v = fmaxf(v, 0.f);
                    out[(size_t)m * ostride + cc] = f2b(v);
                } else {
                    if (cc < 40) out[(size_t)m * 40 + cc] = f2b(v);
                    else { v += bias[cc - 40]; out2[(size_t)m * 40 + (cc - 40)] = f2b(v); }
                }
            }
        }
    }
}

// ---------------------------------------------------------------- 40-dim mean-gather + self + log_softmax
// strict in-row loads: only lanes r<5 touch memory (5 x 16B = exact 80B row)
__global__ __launch_bounds__(256) void k_gather40_lsm(
    const ushort* __restrict__ P, const ushort* __restrict__ R,
    const int* __restrict__ rowptr, const int* __restrict__ col,
    float* __restrict__ out, int nN)
{
    int node = blockIdx.x * 4 + (threadIdx.x >> 6);
    if (node >= nN) return;
    int lane = threadIdx.x & 63;
    int g = lane >> 3;          // edge slot 0..7
    int r = lane & 7;           // 16B chunk -> cols 8r..8r+7 (active r<5 only)
    const bool act = (r < 5);
    int beg = rowptr[node], end = rowptr[node + 1];
    float a[8];
#pragma unroll
    for (int i = 0; i < 8; ++i) a[i] = 0.f;

    for (int j = beg + g; j < end; j += 8) {
        if (act) {
            int s = col[j];
            uint4 v = *(const uint4*)(P + (size_t)s * 40 + r * 8);
            const uint* p = (const uint*)&v;
#pragma unroll
            for (int i = 0; i < 4; ++i) {
                a[2 * i]     += blo(p[i]);
                a[2 * i + 1] += bhi(p[i]);
            }
        }
    }
#pragma unroll
    for (int i = 0; i < 8; ++i) {
        a[i] += __shfl_xor(a[i], 8);
        a[i] += __shfl_xor(a[i], 16);
        a[i] += __shfl_xor(a[i], 32);
    }
    float inv = 1.0f / (float)max(end - beg, 1);
    uint4 rv = make_uint4(0, 0, 0, 0);
    if (act) rv = *(const uint4*)(R + (size_t)node * 40 + r * 8);
    const uint* pr = (const uint*)&rv;
    float vv[8];
    float mx = -INFINITY;
#pragma unroll
    for (int i = 0; i < 8; ++i) {
        float rc = (i & 1) ? bhi(pr[i >> 1]) : blo(pr[i >> 1]);
        int c = r * 8 + i;
        vv[i] = (c < 40) ? (a[i] * inv + rc) : -INFINITY;
        mx = fmaxf(mx, vv[i]);
    }
    mx = fmaxf(mx, __shfl_xor(mx, 1));
    mx = fmaxf(mx, __shfl_xor(mx, 2));
    mx = fmaxf(mx, __shfl_xor(mx, 4));
    float s = 0.f;
#pragma unroll
    for (int i = 0; i < 8; ++i) {
        int c = r * 8 + i;
        if (c < 40) s += __expf(vv[i] - mx);
    }
    s += __shfl_xor(s, 1);
    s += __shfl_xor(s, 2);
    s += __shfl_xor(s, 4);
    float lse = mx + __logf(s);
    if (g == 0 && act) {
        float4 o0 = make_float4(vv[0] - lse, vv[1] - lse, vv[2] - lse, vv[3] - lse);
        float4 o1 = make_float4(vv[4] - lse, vv[5] - lse, vv[6] - lse, vv[7] - lse);
        *(float4*)(out + (size_t)node * 40 + r * 8)     = o0;
        *(float4*)(out + (size_t)node * 40 + r * 8 + 4) = o1;
    }
}

// ---------------------------------------------------------------- launch
extern "C" void kernel_launch(void* const* d_in, const int* in_sizes, int n_in,
                              void* d_out, int out_size, void* d_ws, size_t ws_size,
                              hipStream_t stream) {
    const float* x   = (const float*)d_in[0];
    const int*   ei  = (const int*)d_in[1];
    const float* Wl0 = (const float*)d_in[2];
    const float* Wr0 = (const float*)d_in[3];
    const float* b0  = (const float*)d_in[4];
    const float* Wl1 = (const float*)d_in[5];
    const float* Wr1 = (const float*)d_in[6];
    const float* b1  = (const float*)d_in[7];
    const float* Wl2 = (const float*)d_in[8];
    const float* Wr2 = (const float*)d_in[9];
    const float* b2  = (const float*)d_in[10];
    const int nN = in_sizes[0] / D;
    const int E  = in_sizes[1] / 2;
    const int* src = ei;
    const int* dst = ei + E;

    char* w = (char*)d_ws;
    auto alloc = [&](size_t bytes) { char* p = w; w += (bytes + 255) & ~(size_t)255; return p; };
    int*    deg    = (int*)   alloc((size_t)nN * 4);          // reused as cursor
    int*    rowptr = (int*)   alloc((size_t)(nN + 1) * 4);
    int*    bsum   = (int*)   alloc((size_t)((nN + 255) / 256) * 4);
    int*    col    = (int*)   alloc((size_t)E * 4);
    ushort* AbufA  = (ushort*)alloc((size_t)nN * 256 * 2);    // [agg | feat] bf16
    ushort* AbufB  = (ushort*)alloc((size_t)nN * 256 * 2);
    ushort* Wtg0   = (ushort*)alloc((size_t)128 * 256 * 2);
    ushort* Wtg1   = (ushort*)alloc((size_t)128 * 256 * 2);
    ushort* W2tg   = (ushort*)alloc((size_t)80 * 128 * 2);
    ushort* Pbuf   = AbufB;                    // [N,40] bf16 packed (AbufB dead by then)
    ushort* Rbuf   = AbufB + (size_t)nN * 40;  // [N,40] bf16
    float*  logits = (float*)d_out;
    int*    cursor = deg;

    const int NB        = (nN + 255) / 256;
    const int GATH_BLKS = (nN + 3) / 4;
    const int GEMM_BLKS = (nN + 127) / 128;
    const int PREP_TOT  = nN * 32 + 2 * 128 * 256 + 80 * 128;

    // ---- CSR build + prep (cast + weights)
    hipMemsetAsync(deg, 0, (size_t)nN * 4, stream);
    k_deg  <<<(E + 255) / 256, 256, 0, stream>>>(dst, deg, E);
    k_scan1<<<NB, 256, 0, stream>>>(deg, rowptr, bsum, nN);
    k_scan2<<<1, 512, 0, stream>>>(bsum, NB);
    k_scan3<<<NB, 256, 0, stream>>>(rowptr, bsum, cursor, nN, E);
    k_place<<<(E + 255) / 256, 256, 0, stream>>>(src, dst, cursor, col, E);
    k_prep <<<(PREP_TOT + 255) / 256, 256, 0, stream>>>(
        x, AbufA, nN * 32, Wl0, Wr0, Wl1, Wr1, Wl2, Wr2, Wtg0, Wtg1, W2tg);

    // ---- layer 0
    k_gather128<<<GATH_BLKS, 256, 0, stream>>>(AbufA + 128, AbufA, rowptr, col, nN);
    k_gemm_mfma<128, 256, 264, 0><<<GEMM_BLKS, 256, 0, stream>>>(
        AbufA, 256, Wtg0, b0, AbufB + 128, 256, nullptr, nN);

    // ---- layer 1
    k_gather128<<<GATH_BLKS, 256, 0, stream>>>(AbufB + 128, AbufB, rowptr, col, nN);
    k_gemm_mfma<128, 256, 264, 0><<<GEMM_BLKS, 256, 0, stream>>>(
        AbufB, 256, Wtg1, b1, AbufA + 128, 256, nullptr, nN);   // h1 -> AbufA cols 128+

    // ---- layer 2: project first, then 40-dim gather + log_softmax
    k_gemm_mfma<80, 128, 136, 1><<<GEMM_BLKS, 256, 0, stream>>>(
        AbufA + 128, 256, W2tg, b2, Pbuf, 40, Rbuf, nN);
    k_gather40_lsm<<<GATH_BLKS, 256, 0, stream>>>(Pbuf, Rbuf, rowptr, col, logits, nN);
}

// Round 9
// 381.370 us; speedup vs baseline: 1.0748x; 1.0110x over previous
//
#include <hip/hip_runtime.h>
#include <hip/hip_bf16.h>
#include <math.h>

#define D 128
typedef unsigned int uint;
typedef unsigned short ushort;

using bf16x8 = __attribute__((ext_vector_type(8))) short;
using f32x4  = __attribute__((ext_vector_type(4))) float;

static __device__ __forceinline__ ushort f2b(float f) {
    __hip_bfloat16 h = __float2bfloat16(f);
    return __builtin_bit_cast(ushort, h);
}
static __device__ __forceinline__ float blo(uint u) {
    uint v = u << 16;
    return __builtin_bit_cast(float, v);
}
static __device__ __forceinline__ float bhi(uint u) {
    uint v = u & 0xFFFF0000u;
    return __builtin_bit_cast(float, v);
}

// ---------------------------------------------------------------- build1: deg histogram (idx<Epad) + x fp32->bf16 cast
__global__ void k_build1(const int* __restrict__ dst, int* __restrict__ deg, int E, int Epad,
                         const float* __restrict__ x, ushort* __restrict__ Abuf, int n4) {
    int idx = blockIdx.x * 256 + threadIdx.x;
    if (idx < Epad) {
        if (idx < E) atomicAdd(&deg[dst[idx]], 1);
        return;
    }
    int c = idx - Epad;
    if (c >= n4) return;
    float4 v = *(const float4*)(x + (size_t)c * 4);
    int node = c >> 5;
    int coff = (c & 31) * 4;
    ushort4 o;
    o.x = f2b(v.x); o.y = f2b(v.y); o.z = f2b(v.z); o.w = f2b(v.w);
    *(ushort4*)(Abuf + (size_t)node * 256 + 128 + coff) = o;
}

// ---------------------------------------------------------------- scans
__global__ void k_scan1(const int* __restrict__ deg, int* __restrict__ rowptr,
                        int* __restrict__ bsum, int nN) {
    __shared__ int s[256];
    int tid = threadIdx.x;
    int i = blockIdx.x * 256 + tid;
    int v = (i < nN) ? deg[i] : 0;
    s[tid] = v;
    __syncthreads();
#pragma unroll
    for (int o = 1; o < 256; o <<= 1) {
        int t = (tid >= o) ? s[tid - o] : 0;
        __syncthreads();
        s[tid] += t;
        __syncthreads();
    }
    if (i < nN) rowptr[i] = s[tid] - v;
    if (tid == 255) bsum[blockIdx.x] = s[255];
}

__global__ void k_scan2(int* __restrict__ bsum, int nb) {
    __shared__ int s[512];
    __shared__ int carry_s;
    int tid = threadIdx.x;
    if (tid == 0) carry_s = 0;
    __syncthreads();
    for (int base = 0; base < nb; base += 512) {
        int i = base + tid;
        int v = (i < nb) ? bsum[i] : 0;
        s[tid] = v;
        __syncthreads();
#pragma unroll
        for (int o = 1; o < 512; o <<= 1) {
            int t = (tid >= o) ? s[tid - o] : 0;
            __syncthreads();
            s[tid] += t;
            __syncthreads();
        }
        int carry = carry_s;
        if (i < nb) bsum[i] = s[tid] - v + carry;
        int total = s[511];
        __syncthreads();
        if (tid == 0) carry_s = carry + total;
        __syncthreads();
    }
}

__global__ void k_scan3(int* __restrict__ rowptr, const int* __restrict__ bsum,
                        int* __restrict__ cursor, int nN, int E) {
    int i = blockIdx.x * 256 + threadIdx.x;
    if (i < nN) {
        int r = rowptr[i] + bsum[blockIdx.x];
        rowptr[i] = r;
        cursor[i] = r;
    }
    if (i == 0) rowptr[nN] = E;
}

// ---------------------------------------------------------------- build2: edge place (idx<Epad) + weight prep
__global__ void k_build2(const int* __restrict__ src, const int* __restrict__ dst,
                         int* __restrict__ cursor, int* __restrict__ col, int E, int Epad,
                         const float* __restrict__ Wl0, const float* __restrict__ Wr0,
                         const float* __restrict__ Wl1, const float* __restrict__ Wr1,
                         const float* __restrict__ Wl2, const float* __restrict__ Wr2,
                         ushort* __restrict__ Wtg0, ushort* __restrict__ Wtg1,
                         ushort* __restrict__ W2tg) {
    int idx = blockIdx.x * 256 + threadIdx.x;
    if (idx < Epad) {
        if (idx < E) {
            int pos = atomicAdd(&cursor[dst[idx]], 1);
            col[pos] = src[idx];
        }
        return;
    }
    int w = idx - Epad;
    if (w < 2 * 128 * 256) {
        int which = w >> 15;
        int o = w & 32767;
        int j = o >> 8, k = o & 255;
        const float* Wl = which ? Wl1 : Wl0;
        const float* Wr = which ? Wr1 : Wr0;
        float v = (k < 128) ? Wl[j * 128 + k] : Wr[j * 128 + (k - 128)];
        (which ? Wtg1 : Wtg0)[o] = f2b(v);
    } else {
        int o = w - 2 * 128 * 256;
        if (o >= 80 * 128) return;
        int j = o >> 7, k = o & 127;
        float v = (j < 40) ? Wl2[j * 128 + k] : Wr2[(j - 40) * 128 + k];
        W2tg[o] = f2b(v);
    }
}

// ---------------------------------------------------------------- 128-dim mean-gather, 4 edge slots x 16 lanes x 16B (R4-proven)
__global__ __launch_bounds__(256) void k_gather128(
    const ushort* __restrict__ feat, ushort* __restrict__ agg,
    const int* __restrict__ rowptr, const int* __restrict__ col, int nN)
{
    int node = blockIdx.x * 4 + (threadIdx.x >> 6);
    if (node >= nN) return;
    int lane = threadIdx.x & 63;
    int g = lane >> 4;          // edge slot 0..3
    int r = lane & 15;          // 16B chunk -> dims 8r..8r+7
    int beg = rowptr[node], end = rowptr[node + 1];
    float a[8];
#pragma unroll
    for (int i = 0; i < 8; ++i) a[i] = 0.f;

    int j = beg + g;
    for (; j + 4 < end; j += 8) {          // 8 edges per unrolled iter (2 per slot)
        int s0 = col[j], s1 = col[j + 4];
        uint4 v0 = *(const uint4*)(feat + (size_t)s0 * 256 + r * 8);
        uint4 v1 = *(const uint4*)(feat + (size_t)s1 * 256 + r * 8);
        const uint* p0 = (const uint*)&v0;
        const uint* p1 = (const uint*)&v1;
#pragma unroll
        for (int i = 0; i < 4; ++i) {
            a[2 * i]     += blo(p0[i]) + blo(p1[i]);
            a[2 * i + 1] += bhi(p0[i]) + bhi(p1[i]);
        }
    }
    if (j < end) {
        int s0 = col[j];
        uint4 v0 = *(const uint4*)(feat + (size_t)s0 * 256 + r * 8);
        const uint* p0 = (const uint*)&v0;
#pragma unroll
        for (int i = 0; i < 4; ++i) {
            a[2 * i]     += blo(p0[i]);
            a[2 * i + 1] += bhi(p0[i]);
        }
    }
#pragma unroll
    for (int i = 0; i < 8; ++i) {
        a[i] += __shfl_xor(a[i], 16);
        a[i] += __shfl_xor(a[i], 32);
    }
    if (g == 0) {
        float inv = 1.0f / (float)max(end - beg, 1);
        uint4 o;
        uint* po = (uint*)&o;
#pragma unroll
        for (int i = 0; i < 4; ++i)
            po[i] = (uint)f2b(a[2 * i] * inv) | ((uint)f2b(a[2 * i + 1] * inv) << 16);
        *(uint4*)(agg + (size_t)node * 256 + r * 8) = o;
    }
}

// ---------------------------------------------------------------- MFMA GEMM
// MODE 0: v += bias[j]; relu; out[m*ostride+j].
// MODE 1: j<40 -> P=out[m*40+j]; j>=40 -> R=out2[m*40+j-40] + bias[j-40].
template<int OUTJ, int KDIM, int SW, int MODE>
__global__ __launch_bounds__(256) void k_gemm_mfma(
    const ushort* __restrict__ A, int astride,
    const ushort* __restrict__ Wt, const float* __restrict__ bias,
    ushort* __restrict__ out, int ostride, ushort* __restrict__ out2, int nN)
{
    constexpr int NT = OUTJ / 16;
    constexpr int KSTEPS = KDIM / 32;
    __shared__ __align__(16) ushort Ws[OUTJ * SW];

    const int tid = threadIdx.x;
    constexpr int CHUNKS = OUTJ * KDIM / 8;
#pragma unroll
    for (int c = tid; c < CHUNKS; c += 256) {
        int row = c / (KDIM / 8);
        int ko  = (c % (KDIM / 8)) * 8;
        *(uint4*)(Ws + row * SW + ko) = *(const uint4*)(Wt + row * KDIM + ko);
    }
    __syncthreads();

    const int l = tid & 63, wv = tid >> 6;
    const int q = l >> 4, r = l & 15;
    const long long m0 = (long long)blockIdx.x * 128 + wv * 32;
    const int mA = (int)min(m0 + r, (long long)(nN - 1));
    const int mB = (int)min(m0 + 16 + r, (long long)(nN - 1));
    const ushort* pa = A + (size_t)mA * astride + q * 8;
    const ushort* pb = A + (size_t)mB * astride + q * 8;

    f32x4 acc[2][NT];
#pragma unroll
    for (int mt = 0; mt < 2; ++mt)
#pragma unroll
        for (int nt = 0; nt < NT; ++nt)
            acc[mt][nt] = (f32x4){0.f, 0.f, 0.f, 0.f};

    bf16x8 a0 = *(const bf16x8*)pa;
    bf16x8 a1 = *(const bf16x8*)pb;
#pragma unroll
    for (int ks = 0; ks < KSTEPS; ++ks) {
        bf16x8 a0n = a0, a1n = a1;
        if (ks + 1 < KSTEPS) {
            a0n = *(const bf16x8*)(pa + (ks + 1) * 32);
            a1n = *(const bf16x8*)(pb + (ks + 1) * 32);
        }
#pragma unroll
        for (int nt = 0; nt < NT; ++nt) {
            bf16x8 b = *(const bf16x8*)(Ws + (nt * 16 + r) * SW + ks * 32 + q * 8);
            acc[0][nt] = __builtin_amdgcn_mfma_f32_16x16x32_bf16(a0, b, acc[0][nt], 0, 0, 0);
            acc[1][nt] = __builtin_amdgcn_mfma_f32_16x16x32_bf16(a1, b, acc[1][nt], 0, 0, 0);
        }
        a0 = a0n; a1 = a1n;
    }

#pragma unroll
    for (int mt = 0; mt < 2; ++mt) {
#pragma unroll
        for (int i = 0; i < 4; ++i) {
            long long m = m0 + mt * 16 + q * 4 + i;
            if (m >= nN) continue;
#pragma unroll
            for (int nt = 0; nt < NT; ++nt) {
                int cc = nt * 16 + r;
                float v = acc[mt][nt][i];
                if (MODE == 0) {
                    v += bias[cc];
                    v = fmaxf(v, 0.f);
                    out[(size_t)m * ostride + cc] = f2b(v);
                } else {
                    if (cc < 40) out[(size_t)m * 40 + cc] = f2b(v);
                    else { v += bias[cc - 40]; out2[(size_t)m * 40 + (cc - 40)] = f2b(v); }
                }
            }
        }
    }
}

// ---------------------------------------------------------------- 40-dim mean-gather + self + log_softmax
// strict in-row loads: only lanes r<5 touch memory (5 x 16B = exact 80B row)
__global__ __launch_bounds__(256) void k_gather40_lsm(
    const ushort* __restrict__ P, const ushort* __restrict__ R,
    const int* __restrict__ rowptr, const int* __restrict__ col,
    float* __restrict__ out, int nN)
{
    int node = blockIdx.x * 4 + (threadIdx.x >> 6);
    if (node >= nN) return;
    int lane = threadIdx.x & 63;
    int g = lane >> 3;          // edge slot 0..7
    int r = lane & 7;           // 16B chunk -> cols 8r..8r+7 (active r<5 only)
    const bool act = (r < 5);
    int beg = rowptr[node], end = rowptr[node + 1];
    float a[8];
#pragma unroll
    for (int i = 0; i < 8; ++i) a[i] = 0.f;

    if (act) {
        for (int j = beg + g; j < end; j += 8) {
            int s = col[j];
            uint4 v = *(const uint4*)(P + (size_t)s * 40 + r * 8);
            const uint* p = (const uint*)&v;
#pragma unroll
            for (int i = 0; i < 4; ++i) {
                a[2 * i]     += blo(p[i]);
                a[2 * i + 1] += bhi(p[i]);
            }
        }
    }
#pragma unroll
    for (int i = 0; i < 8; ++i) {
        a[i] += __shfl_xor(a[i], 8);
        a[i] += __shfl_xor(a[i], 16);
        a[i] += __shfl_xor(a[i], 32);
    }
    float inv = 1.0f / (float)max(end - beg, 1);
    uint4 rv = make_uint4(0, 0, 0, 0);
    if (act) rv = *(const uint4*)(R + (size_t)node * 40 + r * 8);
    const uint* pr = (const uint*)&rv;
    float vv[8];
    float mx = -INFINITY;
#pragma unroll
    for (int i = 0; i < 8; ++i) {
        float rc = (i & 1) ? bhi(pr[i >> 1]) : blo(pr[i >> 1]);
        int c = r * 8 + i;
        vv[i] = (c < 40) ? (a[i] * inv + rc) : -INFINITY;
        mx = fmaxf(mx, vv[i]);
    }
    mx = fmaxf(mx, __shfl_xor(mx, 1));
    mx = fmaxf(mx, __shfl_xor(mx, 2));
    mx = fmaxf(mx, __shfl_xor(mx, 4));
    float s = 0.f;
#pragma unroll
    for (int i = 0; i < 8; ++i) {
        int c = r * 8 + i;
        if (c < 40) s += __expf(vv[i] - mx);
    }
    s += __shfl_xor(s, 1);
    s += __shfl_xor(s, 2);
    s += __shfl_xor(s, 4);
    float lse = mx + __logf(s);
    if (g == 0 && act) {
        float4 o0 = make_float4(vv[0] - lse, vv[1] - lse, vv[2] - lse, vv[3] - lse);
        float4 o1 = make_float4(vv[4] - lse, vv[5] - lse, vv[6] - lse, vv[7] - lse);
        *(float4*)(out + (size_t)node * 40 + r * 8)     = o0;
        *(float4*)(out + (size_t)node * 40 + r * 8 + 4) = o1;
    }
}

// ---------------------------------------------------------------- launch
extern "C" void kernel_launch(void* const* d_in, const int* in_sizes, int n_in,
                              void* d_out, int out_size, void* d_ws, size_t ws_size,
                              hipStream_t stream) {
    const float* x   = (const float*)d_in[0];
    const int*   ei  = (const int*)d_in[1];
    const float* Wl0 = (const float*)d_in[2];
    const float* Wr0 = (const float*)d_in[3];
    const float* b0  = (const float*)d_in[4];
    const float* Wl1 = (const float*)d_in[5];
    const float* Wr1 = (const float*)d_in[6];
    const float* b1  = (const float*)d_in[7];
    const float* Wl2 = (const float*)d_in[8];
    const float* Wr2 = (const float*)d_in[9];
    const float* b2  = (const float*)d_in[10];
    const int nN = in_sizes[0] / D;
    const int E  = in_sizes[1] / 2;
    const int* src = ei;
    const int* dst = ei + E;

    char* w = (char*)d_ws;
    auto alloc = [&](size_t bytes) { char* p = w; w += (bytes + 255) & ~(size_t)255; return p; };
    int*    deg    = (int*)   alloc((size_t)nN * 4);          // reused as cursor
    int*    rowptr = (int*)   alloc((size_t)(nN + 1) * 4);
    int*    bsum   = (int*)   alloc((size_t)((nN + 255) / 256) * 4);
    int*    col    = (int*)   alloc((size_t)E * 4);
    ushort* AbufA  = (ushort*)alloc((size_t)nN * 256 * 2);    // [agg | feat] bf16
    ushort* AbufB  = (ushort*)alloc((size_t)nN * 256 * 2);
    ushort* Wtg0   = (ushort*)alloc((size_t)128 * 256 * 2);
    ushort* Wtg1   = (ushort*)alloc((size_t)128 * 256 * 2);
    ushort* W2tg   = (ushort*)alloc((size_t)80 * 128 * 2);
    ushort* Pbuf   = AbufB;                    // [N,40] bf16 packed (AbufB dead by then)
    ushort* Rbuf   = AbufB + (size_t)nN * 40;  // [N,40] bf16
    float*  logits = (float*)d_out;
    int*    cursor = deg;

    const int NB        = (nN + 255) / 256;
    const int GATH_BLKS = (nN + 3) / 4;
    const int GEMM_BLKS = (nN + 127) / 128;
    const int Epad      = (E + 255) & ~255;
    const int B1_TOT    = Epad + nN * 32;
    const int B2_TOT    = Epad + 2 * 128 * 256 + 80 * 128;

    // ---- CSR build + prep, consolidated
    hipMemsetAsync(deg, 0, (size_t)nN * 4, stream);
    k_build1<<<(B1_TOT + 255) / 256, 256, 0, stream>>>(dst, deg, E, Epad, x, AbufA, nN * 32);
    k_scan1<<<NB, 256, 0, stream>>>(deg, rowptr, bsum, nN);
    k_scan2<<<1, 512, 0, stream>>>(bsum, NB);
    k_scan3<<<NB, 256, 0, stream>>>(rowptr, bsum, cursor, nN, E);
    k_build2<<<(B2_TOT + 255) / 256, 256, 0, stream>>>(
        src, dst, cursor, col, E, Epad, Wl0, Wr0, Wl1, Wr1, Wl2, Wr2, Wtg0, Wtg1, W2tg);

    // ---- layer 0
    k_gather128<<<GATH_BLKS, 256, 0, stream>>>(AbufA + 128, AbufA, rowptr, col, nN);
    k_gemm_mfma<128, 256, 264, 0><<<GEMM_BLKS, 256, 0, stream>>>(
        AbufA, 256, Wtg0, b0, AbufB + 128, 256, nullptr, nN);

    // ---- layer 1
    k_gather128<<<GATH_BLKS, 256, 0, stream>>>(AbufB + 128, AbufB, rowptr, col, nN);
    k_gemm_mfma<128, 256, 264, 0><<<GEMM_BLKS, 256, 0, stream>>>(
        AbufB, 256, Wtg1, b1, AbufA + 128, 256, nullptr, nN);   // h1 -> AbufA cols 128+

    // ---- layer 2: project first, then 40-dim gather + log_softmax
    k_gemm_mfma<80, 128, 136, 1><<<GEMM_BLKS, 256, 0, stream>>>(
        AbufA + 128, 256, W2tg, b2, Pbuf, 40, Rbuf, nN);
    k_gather40_lsm<<<GATH_BLKS, 256, 0, stream>>>(Pbuf, Rbuf, rowptr, col, logits, nN);
}